// Round 11
// baseline (65.831 us; speedup 1.0000x reference)
//
#include <hip/hip_runtime.h>
#include <hip/hip_fp16.h>

#define N_ 16
#define C_ 128
#define S_ 16384
#define K_ 64

typedef __attribute__((ext_vector_type(4))) float f32x4;
typedef __attribute__((ext_vector_type(8))) _Float16 f16x8;
typedef __attribute__((ext_vector_type(4))) _Float16 f16x4;

// xT row-swizzle (f16-element granule)
#define SWZ_S(s) ((((s) ^ ((s) >> 3)) & 7) << 3)
// fp8 rows are 64 B; byte-granule XOR swizzle
#define SWZ8(r) (((r) & 7) << 3)

// pack 4 f32 -> 4 fp8 e4m3 bytes (OCP on gfx950)
static __device__ __forceinline__ unsigned int pack_fp8x4(float a, float b,
                                                          float c, float d) {
    int v = __builtin_amdgcn_cvt_pk_fp8_f32(a, b, 0, false);   // low word
    v = __builtin_amdgcn_cvt_pk_fp8_f32(c, d, v, true);        // high word
    return (unsigned int)v;
}

// ---------------------------------------------------------------------------
// Fused v8 = v7 pipeline with fp8 vlad path:
//   S1: stage xT(f16)/xC8(fp8)[b](i) + norms(i) + softmax(i-1)->sst8(fp8,x256)
//   S2: logits(i) MFMA (f16) + vlad(i-1) MFMA (fp8_fp8)
// LDS = 16(xT) + 16(xC8 dbuf) + 4(sst8) + 0.5 = 36.5 KB -> 3 blocks/CU
// (LDS allows 4; unified VGPR+AGPR ~144 caps at 3 waves/SIMD).
// Grid 768 n-aligned (48 blocks/n, 16x6+32x5 tiles); slab flush, no atomics.
// ---------------------------------------------------------------------------
__global__ __launch_bounds__(256, 2) void fused_kernel(
    const float* __restrict__ x, const float* __restrict__ fc_w,
    const float* __restrict__ fc_b, float* __restrict__ vlad_part,
    float* __restrict__ a_part)
{
    __shared__ _Float16 xT[64 * 128];                          // 16 KB [s][c]
    __shared__ __align__(16) unsigned char xC8[2][128 * 64];   // 16 KB [c][s] fp8
    __shared__ __align__(16) unsigned char sst8[64 * 64];      //  4 KB [k][s] fp8 (P*256)
    __shared__ float rns[2][64];                               // 512 B

    const int tid = threadIdx.x;
    const int lane = tid & 63, w = tid >> 6;
    const int lr = lane & 15, g = lane >> 4;
    const int fsw = SWZ8(lr);          // rows of form m*16+lr: (m*16+lr)&7 == lr&7

    // n-aligned ranges: per n, 16 blocks x 6 tiles + 32 blocks x 5 tiles = 256
    const int b = blockIdx.x;
    const int n = b / 48, j = b % 48;
    const int lo  = (j < 16) ? j * 6 : 96 + (j - 16) * 5;   // tile-in-n (64 s each)
    const int cnt = (j < 16) ? 6 : 5;

    // ---- W B-fragments in registers (tile-invariant), f16 ----
    f16x8 wfrag[4][4];
#pragma unroll
    for (int nt = 0; nt < 4; ++nt)
#pragma unroll
        for (int kt = 0; kt < 4; ++kt) {
            const float* wp = fc_w + (nt * 16 + lr) * C_ + kt * 32 + g * 8;
            float4 wa = *(const float4*)wp;
            float4 wb = *(const float4*)(wp + 4);
            f16x8 f;
            f[0] = (_Float16)wa.x; f[1] = (_Float16)wa.y;
            f[2] = (_Float16)wa.z; f[3] = (_Float16)wa.w;
            f[4] = (_Float16)wb.x; f[5] = (_Float16)wb.y;
            f[6] = (_Float16)wb.z; f[7] = (_Float16)wb.w;
            wfrag[nt][kt] = f;
        }
    if (tid < 128) (&rns[0][0])[tid] = 0.f;   // zero both rns buffers

    float bias[4];
#pragma unroll
    for (int nt = 0; nt < 4; ++nt) bias[nt] = fc_b[nt * 16 + lr];
    float a_acc[4] = {0.f, 0.f, 0.f, 0.f};
    f32x4 vacc[8];
#pragma unroll
    for (int nt = 0; nt < 8; ++nt) vacc[nt] = (f32x4){0.f, 0.f, 0.f, 0.f};
    f32x4 accp[4];   // logits(i) carried S2(i) -> S1(i+1)

    const float* xb = x + (size_t)n * C_ * S_;
    const int s4 = tid & 15;
    int cqv[2];
#pragma unroll
    for (int i = 0; i < 2; ++i) cqv[i] = i * 16 + (tid >> 4);

    // prefetch first tile
    float4 pre[2][4];
#pragma unroll
    for (int i = 0; i < 2; ++i)
#pragma unroll
        for (int cc = 0; cc < 4; ++cc)
            pre[i][cc] = *(const float4*)(xb + (size_t)(cqv[i] * 4 + cc) * S_ +
                                          lo * 64 + s4 * 4);

    // softmax(prev) on accp -> sst8 (P*256 fp8), a_acc; rezeroes rns[pit]
    auto softmax_emit = [&](int pit) {
        float rnl[4], ai[4];
#pragma unroll
        for (int r = 0; r < 4; ++r)
            rnl[r] = 1.0f / fmaxf(sqrtf(rns[pit][w * 16 + g * 4 + r]), 1e-12f);
        if (lane < 16) rns[pit][w * 16 + lane] = 0.f;  // same-wave DS order: safe
#pragma unroll
        for (int nt = 0; nt < 4; ++nt)
#pragma unroll
            for (int r = 0; r < 4; ++r)
                accp[nt][r] = __expf(accp[nt][r] * rnl[r] + bias[nt]);
#pragma unroll
        for (int r = 0; r < 4; ++r) {
            float sum = (accp[0][r] + accp[1][r]) + (accp[2][r] + accp[3][r]);
            sum += __shfl_xor(sum, 1);
            sum += __shfl_xor(sum, 2);
            sum += __shfl_xor(sum, 4);
            sum += __shfl_xor(sum, 8);
            float bi = 1.0f / sum;
            ai[r] = bi * rnl[r] * 256.0f;   // P' scaled x256 for fp8 range
#pragma unroll
            for (int nt = 0; nt < 4; ++nt) a_acc[nt] += accp[nt][r] * bi;
        }
#pragma unroll
        for (int nt = 0; nt < 4; ++nt) {
            int k = nt * 16 + lr;
            int sloc = w * 16 + g * 4;
            unsigned int pk = pack_fp8x4(accp[nt][0] * ai[0], accp[nt][1] * ai[1],
                                         accp[nt][2] * ai[2], accp[nt][3] * ai[3]);
            *(unsigned int*)&sst8[k * 64 + (sloc ^ SWZ8(k))] = pk;
        }
    };

#pragma unroll 1
    for (int it = 0; it < cnt; ++it) {
        const int bb = it & 1;
        __syncthreads();   // top: xT/sst8 consumed (S2(it-1)); xC8[bb] consumed

        // ---- S1: stage tile it ----
        float part[4] = {0.f, 0.f, 0.f, 0.f};
#pragma unroll
        for (int i = 0; i < 2; ++i) {
            int cq = cqv[i];
#pragma unroll
            for (int jj = 0; jj < 4; ++jj) {
                float v0 = (&pre[i][0].x)[jj], v1 = (&pre[i][1].x)[jj],
                      v2 = (&pre[i][2].x)[jj], v3 = (&pre[i][3].x)[jj];
                part[jj] += v0 * v0 + v1 * v1 + v2 * v2 + v3 * v3;
                f16x4 p = {(_Float16)v0, (_Float16)v1, (_Float16)v2, (_Float16)v3};
                int s = s4 * 4 + jj;
                *(f16x4*)&xT[s * 128 + ((cq * 4) ^ SWZ_S(s))] = p;
            }
#pragma unroll
            for (int cc = 0; cc < 4; ++cc) {
                int c = cq * 4 + cc;
                unsigned int pk = pack_fp8x4(pre[i][cc].x, pre[i][cc].y,
                                             pre[i][cc].z, pre[i][cc].w);
                *(unsigned int*)&xC8[bb][c * 64 + ((s4 * 4) ^ SWZ8(c))] = pk;
            }
        }
#pragma unroll
        for (int jj = 0; jj < 4; ++jj) {
            part[jj] += __shfl_xor(part[jj], 16);
            part[jj] += __shfl_xor(part[jj], 32);
        }
        if (g == 0) {
#pragma unroll
            for (int jj = 0; jj < 4; ++jj)
                atomicAdd(&rns[it & 1][lr * 4 + jj], part[jj]);
        }
        // softmax(it-1) -> sst8 (overlaps staging)
        if (it > 0) softmax_emit((it - 1) & 1);
        // prefetch tile it+1
        if (it + 1 < cnt) {
            const float* xb2 = xb + (lo + it + 1) * 64;
#pragma unroll
            for (int i = 0; i < 2; ++i)
#pragma unroll
                for (int cc = 0; cc < 4; ++cc)
                    pre[i][cc] = *(const float4*)(xb2 + (size_t)(cqv[i] * 4 + cc) * S_ + s4 * 4);
        }
        __syncthreads();   // xT/xC8[bb]/sst8/rns visible

        // ---- S2: pure MFMA + LDS reads ----
#pragma unroll
        for (int nt = 0; nt < 4; ++nt) accp[nt] = (f32x4){0.f, 0.f, 0.f, 0.f};
        __builtin_amdgcn_s_setprio(1);
#pragma unroll
        for (int kt = 0; kt < 4; ++kt) {
            const int co = kt * 32 + g * 8;
            const int sa = w * 16 + lr;
            f16x8 af = *(const f16x8*)&xT[sa * 128 + (co ^ SWZ_S(sa))];
#pragma unroll
            for (int nt = 0; nt < 4; ++nt)
                accp[nt] = __builtin_amdgcn_mfma_f32_16x16x32_f16(af, wfrag[nt][kt], accp[nt], 0, 0, 0);
        }
        if (it > 0) {
            const unsigned char* xcp = xC8[bb ^ 1];
#pragma unroll
            for (int kt = 0; kt < 2; ++kt) {
                const int so = kt * 32 + g * 8;   // byte == s-element offset
                long pa = *(const long*)&sst8[(w * 16 + lr) * 64 + (so ^ fsw)];
#pragma unroll
                for (int nt = 0; nt < 8; ++nt) {
                    long xv = *(const long*)&xcp[(nt * 16 + lr) * 64 + (so ^ fsw)];
                    vacc[nt] = __builtin_amdgcn_mfma_f32_16x16x32_fp8_fp8(pa, xv, vacc[nt], 0, 0, 0);
                }
            }
        }
        __builtin_amdgcn_s_setprio(0);
    }

    // ---- epilogue: softmax(cnt-1) -> sst8, then vlad(cnt-1) ----
    const int lastb = (cnt - 1) & 1;
    __syncthreads();
    softmax_emit(lastb);
    __syncthreads();
    {
        const unsigned char* xcp = xC8[lastb];
#pragma unroll
        for (int kt = 0; kt < 2; ++kt) {
            const int so = kt * 32 + g * 8;
            long pa = *(const long*)&sst8[(w * 16 + lr) * 64 + (so ^ fsw)];
#pragma unroll
            for (int nt = 0; nt < 8; ++nt) {
                long xv = *(const long*)&xcp[(nt * 16 + lr) * 64 + (so ^ fsw)];
                vacc[nt] = __builtin_amdgcn_mfma_f32_16x16x32_fp8_fp8(pa, xv, vacc[nt], 0, 0, 0);
            }
        }
    }

    // ---- flush: plain stores to this block's private slab (unscale /256) ----
    float* vp = vlad_part + (size_t)b * (K_ * C_) + (w * 16) * C_;
#pragma unroll
    for (int nt = 0; nt < 8; ++nt)
#pragma unroll
        for (int r = 0; r < 4; ++r)
            vp[(g * 4 + r) * C_ + nt * 16 + lr] = vacc[nt][r] * (1.0f / 256.0f);
#pragma unroll
    for (int nt = 0; nt < 4; ++nt) {
        a_acc[nt] += __shfl_xor(a_acc[nt], 16);
        a_acc[nt] += __shfl_xor(a_acc[nt], 32);
    }
    if (lane < 16) {
#pragma unroll
        for (int nt = 0; nt < 4; ++nt)
            a_part[b * 256 + w * 64 + nt * 16 + lr] = a_acc[nt];
    }
}

// ---------------------------------------------------------------------------
// Reduce: vlad_sum[n][e] = sum_{j<48} vlad_part[n*48+j][e]
// ---------------------------------------------------------------------------
__global__ __launch_bounds__(256) void reduce_kernel(
    const float* __restrict__ vlad_part, float* __restrict__ vlad_sum)
{
    const int n = blockIdx.x >> 5, g8 = blockIdx.x & 31;
    const int e = g8 * 256 + threadIdx.x;        // (k*128+c)
    const float* p = vlad_part + (size_t)(n * 48) * (K_ * C_) + e;
    float acc = 0.f;
#pragma unroll
    for (int jj = 0; jj < 48; ++jj) acc += p[(size_t)jj * (K_ * C_)];
    vlad_sum[n * (K_ * C_) + e] = acc;
}

// ---------------------------------------------------------------------------
// Finalize: a_sum reduce (48 chunks x 4 waves); vlad -= a_sum*centroids;
// intra-norm over C; global norm. Grid 16 x 1024; t: k=t>>4, q=t&15.
// ---------------------------------------------------------------------------
__global__ __launch_bounds__(1024) void finalize_kernel(
    const float* __restrict__ vlad_sum, const float* __restrict__ a_part,
    const float* __restrict__ centroids, float* __restrict__ out)
{
    __shared__ float red[16];
    const int n = blockIdx.x;
    const int t = threadIdx.x;
    const int k = t >> 4, q = t & 15;

    float av = 0.f;
#pragma unroll
    for (int cc = 0; cc < 3; ++cc) {
        int ch = q * 3 + cc;
        const float* ap = a_part + (size_t)(n * 48 + ch) * 256 + k;
#pragma unroll
        for (int ww = 0; ww < 4; ++ww) av += ap[ww * 64];
    }
    av += __shfl_xor(av, 1);
    av += __shfl_xor(av, 2);
    av += __shfl_xor(av, 4);
    av += __shfl_xor(av, 8);

    const float* vp = vlad_sum + (size_t)n * (K_ * C_) + k * C_;
    const float* cp = centroids + k * C_;
    float v[8];
    float ssq = 0.f;
#pragma unroll
    for (int jj = 0; jj < 8; ++jj) {
        int c = q + 16 * jj;
        float val = vp[c] - av * cp[c];
        v[jj] = val;
        ssq += val * val;
    }
    ssq += __shfl_xor(ssq, 1);
    ssq += __shfl_xor(ssq, 2);
    ssq += __shfl_xor(ssq, 4);
    ssq += __shfl_xor(ssq, 8);
    const float inv1 = 1.0f / fmaxf(sqrtf(ssq), 1e-12f);

    float gp = (q == 0) ? ssq * inv1 * inv1 : 0.f;
#pragma unroll
    for (int off = 1; off < 64; off <<= 1) gp += __shfl_xor(gp, off);
    if ((t & 63) == 0) red[t >> 6] = gp;
    __syncthreads();
    float G = 0.f;
#pragma unroll
    for (int i = 0; i < 16; ++i) G += red[i];
    const float ginv = 1.0f / fmaxf(sqrtf(G), 1e-12f);

    float* op = out + (size_t)n * (K_ * C_) + k * C_;
#pragma unroll
    for (int jj = 0; jj < 8; ++jj) op[q + 16 * jj] = v[jj] * inv1 * ginv;
}

extern "C" void kernel_launch(void* const* d_in, const int* in_sizes, int n_in,
                              void* d_out, int out_size, void* d_ws, size_t ws_size,
                              hipStream_t stream) {
    const float* x     = (const float*)d_in[0];
    const float* fc_w  = (const float*)d_in[1];
    const float* fc_b  = (const float*)d_in[2];
    const float* cent  = (const float*)d_in[3];
    float* out = (float*)d_out;

    char* ws = (char*)d_ws;
    float* vlad_part = (float*)ws;                                    // 25.2 MB
    float* a_part    = (float*)(ws + (size_t)768 * K_ * C_ * 4);      // 768 KB
    float* vlad_sum  = (float*)(ws + (size_t)768 * K_ * C_ * 4 + 786432);

    fused_kernel<<<768, 256, 0, stream>>>(x, fc_w, fc_b, vlad_part, a_part);
    reduce_kernel<<<512, 256, 0, stream>>>(vlad_part, vlad_sum);
    finalize_kernel<<<N_, 1024, 0, stream>>>(vlad_sum, a_part, cent, out);
}

// Round 12
// 51.580 us; speedup vs baseline: 1.2763x; 1.2763x over previous
//
#include <hip/hip_runtime.h>
#include <hip/hip_fp16.h>

#define N_ 16
#define C_ 128
#define S_ 16384
#define K_ 64

typedef __attribute__((ext_vector_type(4))) float f32x4;
typedef __attribute__((ext_vector_type(8))) _Float16 f16x8;
typedef __attribute__((ext_vector_type(4))) _Float16 f16x4;

// f16-granule row swizzle (xT, W)
#define SWZ_S(s) ((((s) ^ ((s) >> 3)) & 7) << 3)
#define SWZ16(k) (((k) & 7) << 3)
// fp8 rows are 64 B; byte-granule XOR swizzle
#define SWZ8(r) (((r) & 7) << 3)

// pack 4 f32 -> 4 fp8 e4m3 bytes (OCP on gfx950)
static __device__ __forceinline__ unsigned int pack_fp8x4(float a, float b,
                                                          float c, float d) {
    int v = __builtin_amdgcn_cvt_pk_fp8_f32(a, b, 0, false);
    v = __builtin_amdgcn_cvt_pk_fp8_f32(c, d, v, true);
    return (unsigned int)v;
}

// ---------------------------------------------------------------------------
// Fused v9: occupancy build. Total regs <=128 (W in LDS, not 64 VGPRs) AND
// LDS = 16(xT) + 16(W) + 16(xC8 dbuf) + 4(sst8) + 0.5 = 52.5 KB -> 3 blk/CU,
// 12 waves/CU (reg tier allows 4 waves/SIMD; LDS binds at 3).
//   S1: stage xT(f16)+xC8(fp8)[b](i) + norms + softmax(i-1)->sst8 + prefetch
//   S2: logits(i) MFMA (f16, W from LDS) + vlad(i-1) MFMA (fp8)
// Grid 768: b<256 -> 6 tiles (dispatch first), b>=256 -> 5 tiles; slab flush.
// ---------------------------------------------------------------------------
__global__ __launch_bounds__(256, 2) void fused_kernel(
    const float* __restrict__ x, const float* __restrict__ fc_w,
    const float* __restrict__ fc_b, float* __restrict__ vlad_part,
    float* __restrict__ a_part)
{
    __shared__ __align__(16) _Float16 xT[64 * 128];            // 16 KB [s][c]
    __shared__ __align__(16) _Float16 Wlds[64 * 128];          // 16 KB [k][c]
    __shared__ __align__(16) unsigned char xC8[2][128 * 64];   // 16 KB [c][s] fp8
    __shared__ __align__(16) unsigned char sst8[64 * 64];      //  4 KB [k][s] fp8 (P*256)
    __shared__ float rns[2][64];                               // 512 B

    const int tid = threadIdx.x;
    const int lane = tid & 63, w = tid >> 6;
    const int lr = lane & 15, g = lane >> 4;
    const int fsw8 = SWZ8(lr);     // fp8 rows of form m*16+lr
    const int fsw16 = SWZ16(lr);   // f16 rows of form m*16+lr

    // block -> (n, tile range, slab slot); 6-tilers are blocks 0..255
    const int b = blockIdx.x;
    const int n     = (b < 256) ? (b >> 4) : ((b - 256) >> 5);
    const int lo    = (b < 256) ? (b & 15) * 6 : 96 + ((b - 256) & 31) * 5;
    const int cnt   = (b < 256) ? 6 : 5;
    const int jslot = (b < 256) ? (b & 15) : 16 + ((b - 256) & 31);
    const int sl    = n * 48 + jslot;

    // ---- stage W once into LDS (f16, swizzled) ----
#pragma unroll
    for (int i = 0; i < 8; ++i) {
        int idx = i * 256 + tid;
        int c4 = idx & 31, k = idx >> 5;
        float4 wv = *(const float4*)(fc_w + k * C_ + c4 * 4);
        f16x4 hi = {(_Float16)wv.x, (_Float16)wv.y, (_Float16)wv.z, (_Float16)wv.w};
        *(f16x4*)&Wlds[k * 128 + ((c4 * 4) ^ SWZ16(k))] = hi;
    }
    if (tid < 128) (&rns[0][0])[tid] = 0.f;

    float bias[4];
#pragma unroll
    for (int nt = 0; nt < 4; ++nt) bias[nt] = fc_b[nt * 16 + lr];
    float a_acc[4] = {0.f, 0.f, 0.f, 0.f};
    f32x4 vacc[8];
#pragma unroll
    for (int nt = 0; nt < 8; ++nt) vacc[nt] = (f32x4){0.f, 0.f, 0.f, 0.f};
    f32x4 accp[4];   // logits(i) carried S2(i) -> S1(i+1)

    const float* xb = x + (size_t)n * C_ * S_;
    const int s4 = tid & 15;
    int cqv[2];
#pragma unroll
    for (int i = 0; i < 2; ++i) cqv[i] = i * 16 + (tid >> 4);

    // prefetch first tile
    float4 pre[2][4];
#pragma unroll
    for (int i = 0; i < 2; ++i)
#pragma unroll
        for (int cc = 0; cc < 4; ++cc)
            pre[i][cc] = *(const float4*)(xb + (size_t)(cqv[i] * 4 + cc) * S_ +
                                          lo * 64 + s4 * 4);

    auto softmax_emit = [&](int pit) {
        float rnl[4], ai[4];
#pragma unroll
        for (int r = 0; r < 4; ++r)
            rnl[r] = 1.0f / fmaxf(sqrtf(rns[pit][w * 16 + g * 4 + r]), 1e-12f);
        if (lane < 16) rns[pit][w * 16 + lane] = 0.f;  // same-wave DS order: safe
#pragma unroll
        for (int nt = 0; nt < 4; ++nt)
#pragma unroll
            for (int r = 0; r < 4; ++r)
                accp[nt][r] = __expf(accp[nt][r] * rnl[r] + bias[nt]);
#pragma unroll
        for (int r = 0; r < 4; ++r) {
            float sum = (accp[0][r] + accp[1][r]) + (accp[2][r] + accp[3][r]);
            sum += __shfl_xor(sum, 1);
            sum += __shfl_xor(sum, 2);
            sum += __shfl_xor(sum, 4);
            sum += __shfl_xor(sum, 8);
            float bi = 1.0f / sum;
            ai[r] = bi * rnl[r] * 256.0f;   // P' scaled x256 for fp8 range
#pragma unroll
            for (int nt = 0; nt < 4; ++nt) a_acc[nt] += accp[nt][r] * bi;
        }
#pragma unroll
        for (int nt = 0; nt < 4; ++nt) {
            int k = nt * 16 + lr;
            int sloc = w * 16 + g * 4;
            unsigned int pk = pack_fp8x4(accp[nt][0] * ai[0], accp[nt][1] * ai[1],
                                         accp[nt][2] * ai[2], accp[nt][3] * ai[3]);
            *(unsigned int*)&sst8[k * 64 + (sloc ^ SWZ8(k))] = pk;
        }
    };

#pragma unroll 1
    for (int it = 0; it < cnt; ++it) {
        const int bb = it & 1;
        __syncthreads();   // top: xT/sst8 consumed (S2(it-1)); xC8[bb] free

        // ---- S1: stage tile it ----
        float part[4] = {0.f, 0.f, 0.f, 0.f};
#pragma unroll
        for (int i = 0; i < 2; ++i) {
            int cq = cqv[i];
#pragma unroll
            for (int jj = 0; jj < 4; ++jj) {
                float v0 = (&pre[i][0].x)[jj], v1 = (&pre[i][1].x)[jj],
                      v2 = (&pre[i][2].x)[jj], v3 = (&pre[i][3].x)[jj];
                part[jj] += v0 * v0 + v1 * v1 + v2 * v2 + v3 * v3;
                f16x4 p = {(_Float16)v0, (_Float16)v1, (_Float16)v2, (_Float16)v3};
                int s = s4 * 4 + jj;
                *(f16x4*)&xT[s * 128 + ((cq * 4) ^ SWZ_S(s))] = p;
            }
#pragma unroll
            for (int cc = 0; cc < 4; ++cc) {
                int c = cq * 4 + cc;
                unsigned int pk = pack_fp8x4(pre[i][cc].x, pre[i][cc].y,
                                             pre[i][cc].z, pre[i][cc].w);
                *(unsigned int*)&xC8[bb][c * 64 + ((s4 * 4) ^ SWZ8(c))] = pk;
            }
        }
#pragma unroll
        for (int jj = 0; jj < 4; ++jj) {
            part[jj] += __shfl_xor(part[jj], 16);
            part[jj] += __shfl_xor(part[jj], 32);
        }
        if (g == 0) {
#pragma unroll
            for (int jj = 0; jj < 4; ++jj)
                atomicAdd(&rns[it & 1][lr * 4 + jj], part[jj]);
        }
        if (it > 0) softmax_emit((it - 1) & 1);
        if (it + 1 < cnt) {
            const float* xb2 = xb + (lo + it + 1) * 64;
#pragma unroll
            for (int i = 0; i < 2; ++i)
#pragma unroll
                for (int cc = 0; cc < 4; ++cc)
                    pre[i][cc] = *(const float4*)(xb2 + (size_t)(cqv[i] * 4 + cc) * S_ + s4 * 4);
        }
        __syncthreads();   // xT/xC8[bb]/sst8/rns visible

        // ---- S2: pure MFMA + LDS reads ----
#pragma unroll
        for (int nt = 0; nt < 4; ++nt) accp[nt] = (f32x4){0.f, 0.f, 0.f, 0.f};
        __builtin_amdgcn_s_setprio(1);
#pragma unroll
        for (int kt = 0; kt < 4; ++kt) {
            const int co = kt * 32 + g * 8;
            const int sa = w * 16 + lr;
            f16x8 af = *(const f16x8*)&xT[sa * 128 + (co ^ SWZ_S(sa))];
#pragma unroll
            for (int nt = 0; nt < 4; ++nt) {
                f16x8 wf = *(const f16x8*)&Wlds[(nt * 16 + lr) * 128 + (co ^ fsw16)];
                accp[nt] = __builtin_amdgcn_mfma_f32_16x16x32_f16(af, wf, accp[nt], 0, 0, 0);
            }
        }
        if (it > 0) {
            const unsigned char* xcp = xC8[bb ^ 1];
#pragma unroll
            for (int kt = 0; kt < 2; ++kt) {
                const int so = kt * 32 + g * 8;
                long pa = *(const long*)&sst8[(w * 16 + lr) * 64 + (so ^ fsw8)];
#pragma unroll
                for (int nt = 0; nt < 8; ++nt) {
                    long xv = *(const long*)&xcp[(nt * 16 + lr) * 64 + (so ^ fsw8)];
                    vacc[nt] = __builtin_amdgcn_mfma_f32_16x16x32_fp8_fp8(pa, xv, vacc[nt], 0, 0, 0);
                }
            }
        }
        __builtin_amdgcn_s_setprio(0);
    }

    // ---- epilogue: softmax(cnt-1) -> sst8, then vlad(cnt-1) ----
    const int lastb = (cnt - 1) & 1;
    __syncthreads();
    softmax_emit(lastb);
    __syncthreads();
    {
        const unsigned char* xcp = xC8[lastb];
#pragma unroll
        for (int kt = 0; kt < 2; ++kt) {
            const int so = kt * 32 + g * 8;
            long pa = *(const long*)&sst8[(w * 16 + lr) * 64 + (so ^ fsw8)];
#pragma unroll
            for (int nt = 0; nt < 8; ++nt) {
                long xv = *(const long*)&xcp[(nt * 16 + lr) * 64 + (so ^ fsw8)];
                vacc[nt] = __builtin_amdgcn_mfma_f32_16x16x32_fp8_fp8(pa, xv, vacc[nt], 0, 0, 0);
            }
        }
    }

    // ---- flush: plain stores to this block's slab (unscale /256) ----
    float* vp = vlad_part + (size_t)sl * (K_ * C_) + (w * 16) * C_;
#pragma unroll
    for (int nt = 0; nt < 8; ++nt)
#pragma unroll
        for (int r = 0; r < 4; ++r)
            vp[(g * 4 + r) * C_ + nt * 16 + lr] = vacc[nt][r] * (1.0f / 256.0f);
#pragma unroll
    for (int nt = 0; nt < 4; ++nt) {
        a_acc[nt] += __shfl_xor(a_acc[nt], 16);
        a_acc[nt] += __shfl_xor(a_acc[nt], 32);
    }
    if (lane < 16) {
#pragma unroll
        for (int nt = 0; nt < 4; ++nt)
            a_part[sl * 256 + w * 64 + nt * 16 + lr] = a_acc[nt];
    }
}

// ---------------------------------------------------------------------------
// Reduce: vlad_sum[n][e] = sum_{j<48} vlad_part[n*48+j][e]
// ---------------------------------------------------------------------------
__global__ __launch_bounds__(256) void reduce_kernel(
    const float* __restrict__ vlad_part, float* __restrict__ vlad_sum)
{
    const int n = blockIdx.x >> 5, g8 = blockIdx.x & 31;
    const int e = g8 * 256 + threadIdx.x;
    const float* p = vlad_part + (size_t)(n * 48) * (K_ * C_) + e;
    float acc = 0.f;
#pragma unroll
    for (int jj = 0; jj < 48; ++jj) acc += p[(size_t)jj * (K_ * C_)];
    vlad_sum[n * (K_ * C_) + e] = acc;
}

// ---------------------------------------------------------------------------
// Finalize: a_sum reduce; vlad -= a_sum*centroids; intra-norm; global norm.
// ---------------------------------------------------------------------------
__global__ __launch_bounds__(1024) void finalize_kernel(
    const float* __restrict__ vlad_sum, const float* __restrict__ a_part,
    const float* __restrict__ centroids, float* __restrict__ out)
{
    __shared__ float red[16];
    const int n = blockIdx.x;
    const int t = threadIdx.x;
    const int k = t >> 4, q = t & 15;

    float av = 0.f;
#pragma unroll
    for (int cc = 0; cc < 3; ++cc) {
        int ch = q * 3 + cc;
        const float* ap = a_part + (size_t)(n * 48 + ch) * 256 + k;
#pragma unroll
        for (int ww = 0; ww < 4; ++ww) av += ap[ww * 64];
    }
    av += __shfl_xor(av, 1);
    av += __shfl_xor(av, 2);
    av += __shfl_xor(av, 4);
    av += __shfl_xor(av, 8);

    const float* vp = vlad_sum + (size_t)n * (K_ * C_) + k * C_;
    const float* cp = centroids + k * C_;
    float v[8];
    float ssq = 0.f;
#pragma unroll
    for (int jj = 0; jj < 8; ++jj) {
        int c = q + 16 * jj;
        float val = vp[c] - av * cp[c];
        v[jj] = val;
        ssq += val * val;
    }
    ssq += __shfl_xor(ssq, 1);
    ssq += __shfl_xor(ssq, 2);
    ssq += __shfl_xor(ssq, 4);
    ssq += __shfl_xor(ssq, 8);
    const float inv1 = 1.0f / fmaxf(sqrtf(ssq), 1e-12f);

    float gp = (q == 0) ? ssq * inv1 * inv1 : 0.f;
#pragma unroll
    for (int off = 1; off < 64; off <<= 1) gp += __shfl_xor(gp, off);
    if ((t & 63) == 0) red[t >> 6] = gp;
    __syncthreads();
    float G = 0.f;
#pragma unroll
    for (int i = 0; i < 16; ++i) G += red[i];
    const float ginv = 1.0f / fmaxf(sqrtf(G), 1e-12f);

    float* op = out + (size_t)n * (K_ * C_) + k * C_;
#pragma unroll
    for (int jj = 0; jj < 8; ++jj) op[q + 16 * jj] = v[jj] * inv1 * ginv;
}

extern "C" void kernel_launch(void* const* d_in, const int* in_sizes, int n_in,
                              void* d_out, int out_size, void* d_ws, size_t ws_size,
                              hipStream_t stream) {
    const float* x     = (const float*)d_in[0];
    const float* fc_w  = (const float*)d_in[1];
    const float* fc_b  = (const float*)d_in[2];
    const float* cent  = (const float*)d_in[3];
    float* out = (float*)d_out;

    char* ws = (char*)d_ws;
    float* vlad_part = (float*)ws;                                    // 25.2 MB
    float* a_part    = (float*)(ws + (size_t)768 * K_ * C_ * 4);      // 768 KB
    float* vlad_sum  = (float*)(ws + (size_t)768 * K_ * C_ * 4 + 786432);

    fused_kernel<<<768, 256, 0, stream>>>(x, fc_w, fc_b, vlad_part, a_part);
    reduce_kernel<<<512, 256, 0, stream>>>(vlad_part, vlad_sum);
    finalize_kernel<<<N_, 1024, 0, stream>>>(vlad_sum, a_part, cent, out);
}

// Round 13
// 51.518 us; speedup vs baseline: 1.2778x; 1.0012x over previous
//
#include <hip/hip_runtime.h>
#include <hip/hip_fp16.h>

#define N_ 16
#define C_ 128
#define S_ 16384
#define K_ 64

typedef __attribute__((ext_vector_type(4))) float f32x4;
typedef __attribute__((ext_vector_type(8))) _Float16 f16x8;
typedef __attribute__((ext_vector_type(4))) _Float16 f16x4;

// f16-granule row swizzle (xT, W)
#define SWZ_S(s) ((((s) ^ ((s) >> 3)) & 7) << 3)
#define SWZ16(k) (((k) & 7) << 3)
// fp8 rows are 64 B; byte-granule XOR swizzle
#define SWZ8(r) (((r) & 7) << 3)

// pack 4 f32 -> 4 fp8 e4m3 bytes (OCP on gfx950)
static __device__ __forceinline__ unsigned int pack_fp8x4(float a, float b,
                                                          float c, float d) {
    int v = __builtin_amdgcn_cvt_pk_fp8_f32(a, b, 0, false);
    v = __builtin_amdgcn_cvt_pk_fp8_f32(c, d, v, true);
    return (unsigned int)v;
}

// ---------------------------------------------------------------------------
// Fused v10 = v9 with __launch_bounds__(256,3): forces the allocator into the
// ~84-arch-VGPR tier (r7 evidence). Unlike r7, wfrag is in LDS, so the arch
// live set (~75) fits: total unified ~84+48acc = 132 -> 3 waves/SIMD, and
// LDS 52.5 KB -> exactly 3 blocks/CU with the 768 grid (zero tail).
// Tripwire: FETCH > 80 MB => spill came back => revert + shrink pre.
// ---------------------------------------------------------------------------
__global__ __launch_bounds__(256, 3) void fused_kernel(
    const float* __restrict__ x, const float* __restrict__ fc_w,
    const float* __restrict__ fc_b, float* __restrict__ vlad_part,
    float* __restrict__ a_part)
{
    __shared__ __align__(16) _Float16 xT[64 * 128];            // 16 KB [s][c]
    __shared__ __align__(16) _Float16 Wlds[64 * 128];          // 16 KB [k][c]
    __shared__ __align__(16) unsigned char xC8[2][128 * 64];   // 16 KB [c][s] fp8
    __shared__ __align__(16) unsigned char sst8[64 * 64];      //  4 KB [k][s] fp8 (P*256)
    __shared__ float rns[2][64];                               // 512 B

    const int tid = threadIdx.x;
    const int lane = tid & 63, w = tid >> 6;
    const int lr = lane & 15, g = lane >> 4;
    const int fsw8 = SWZ8(lr);     // fp8 rows of form m*16+lr
    const int fsw16 = SWZ16(lr);   // f16 rows of form m*16+lr

    // block -> (n, tile range, slab slot); 6-tilers are blocks 0..255
    const int b = blockIdx.x;
    const int n     = (b < 256) ? (b >> 4) : ((b - 256) >> 5);
    const int lo    = (b < 256) ? (b & 15) * 6 : 96 + ((b - 256) & 31) * 5;
    const int cnt   = (b < 256) ? 6 : 5;
    const int jslot = (b < 256) ? (b & 15) : 16 + ((b - 256) & 31);
    const int sl    = n * 48 + jslot;

    // ---- stage W once into LDS (f16, swizzled) ----
#pragma unroll
    for (int i = 0; i < 8; ++i) {
        int idx = i * 256 + tid;
        int c4 = idx & 31, k = idx >> 5;
        float4 wv = *(const float4*)(fc_w + k * C_ + c4 * 4);
        f16x4 hi = {(_Float16)wv.x, (_Float16)wv.y, (_Float16)wv.z, (_Float16)wv.w};
        *(f16x4*)&Wlds[k * 128 + ((c4 * 4) ^ SWZ16(k))] = hi;
    }
    if (tid < 128) (&rns[0][0])[tid] = 0.f;

    float bias[4];
#pragma unroll
    for (int nt = 0; nt < 4; ++nt) bias[nt] = fc_b[nt * 16 + lr];
    float a_acc[4] = {0.f, 0.f, 0.f, 0.f};
    f32x4 vacc[8];
#pragma unroll
    for (int nt = 0; nt < 8; ++nt) vacc[nt] = (f32x4){0.f, 0.f, 0.f, 0.f};
    f32x4 accp[4];   // logits(i) carried S2(i) -> S1(i+1)

    const float* xb = x + (size_t)n * C_ * S_;
    const int s4 = tid & 15;
    int cqv[2];
#pragma unroll
    for (int i = 0; i < 2; ++i) cqv[i] = i * 16 + (tid >> 4);

    // prefetch first tile
    float4 pre[2][4];
#pragma unroll
    for (int i = 0; i < 2; ++i)
#pragma unroll
        for (int cc = 0; cc < 4; ++cc)
            pre[i][cc] = *(const float4*)(xb + (size_t)(cqv[i] * 4 + cc) * S_ +
                                          lo * 64 + s4 * 4);

    auto softmax_emit = [&](int pit) {
        float rnl[4], ai[4];
#pragma unroll
        for (int r = 0; r < 4; ++r)
            rnl[r] = 1.0f / fmaxf(sqrtf(rns[pit][w * 16 + g * 4 + r]), 1e-12f);
        if (lane < 16) rns[pit][w * 16 + lane] = 0.f;  // same-wave DS order: safe
#pragma unroll
        for (int nt = 0; nt < 4; ++nt)
#pragma unroll
            for (int r = 0; r < 4; ++r)
                accp[nt][r] = __expf(accp[nt][r] * rnl[r] + bias[nt]);
#pragma unroll
        for (int r = 0; r < 4; ++r) {
            float sum = (accp[0][r] + accp[1][r]) + (accp[2][r] + accp[3][r]);
            sum += __shfl_xor(sum, 1);
            sum += __shfl_xor(sum, 2);
            sum += __shfl_xor(sum, 4);
            sum += __shfl_xor(sum, 8);
            float bi = 1.0f / sum;
            ai[r] = bi * rnl[r] * 256.0f;   // P' scaled x256 for fp8 range
#pragma unroll
            for (int nt = 0; nt < 4; ++nt) a_acc[nt] += accp[nt][r] * bi;
        }
#pragma unroll
        for (int nt = 0; nt < 4; ++nt) {
            int k = nt * 16 + lr;
            int sloc = w * 16 + g * 4;
            unsigned int pk = pack_fp8x4(accp[nt][0] * ai[0], accp[nt][1] * ai[1],
                                         accp[nt][2] * ai[2], accp[nt][3] * ai[3]);
            *(unsigned int*)&sst8[k * 64 + (sloc ^ SWZ8(k))] = pk;
        }
    };

#pragma unroll 1
    for (int it = 0; it < cnt; ++it) {
        const int bb = it & 1;
        __syncthreads();   // top: xT/sst8 consumed (S2(it-1)); xC8[bb] free

        // ---- S1: stage tile it ----
        float part[4] = {0.f, 0.f, 0.f, 0.f};
#pragma unroll
        for (int i = 0; i < 2; ++i) {
            int cq = cqv[i];
#pragma unroll
            for (int jj = 0; jj < 4; ++jj) {
                float v0 = (&pre[i][0].x)[jj], v1 = (&pre[i][1].x)[jj],
                      v2 = (&pre[i][2].x)[jj], v3 = (&pre[i][3].x)[jj];
                part[jj] += v0 * v0 + v1 * v1 + v2 * v2 + v3 * v3;
                f16x4 p = {(_Float16)v0, (_Float16)v1, (_Float16)v2, (_Float16)v3};
                int s = s4 * 4 + jj;
                *(f16x4*)&xT[s * 128 + ((cq * 4) ^ SWZ_S(s))] = p;
            }
#pragma unroll
            for (int cc = 0; cc < 4; ++cc) {
                int c = cq * 4 + cc;
                unsigned int pk = pack_fp8x4(pre[i][cc].x, pre[i][cc].y,
                                             pre[i][cc].z, pre[i][cc].w);
                *(unsigned int*)&xC8[bb][c * 64 + ((s4 * 4) ^ SWZ8(c))] = pk;
            }
        }
#pragma unroll
        for (int jj = 0; jj < 4; ++jj) {
            part[jj] += __shfl_xor(part[jj], 16);
            part[jj] += __shfl_xor(part[jj], 32);
        }
        if (g == 0) {
#pragma unroll
            for (int jj = 0; jj < 4; ++jj)
                atomicAdd(&rns[it & 1][lr * 4 + jj], part[jj]);
        }
        if (it > 0) softmax_emit((it - 1) & 1);
        if (it + 1 < cnt) {
            const float* xb2 = xb + (lo + it + 1) * 64;
#pragma unroll
            for (int i = 0; i < 2; ++i)
#pragma unroll
                for (int cc = 0; cc < 4; ++cc)
                    pre[i][cc] = *(const float4*)(xb2 + (size_t)(cqv[i] * 4 + cc) * S_ + s4 * 4);
        }
        __syncthreads();   // xT/xC8[bb]/sst8/rns visible

        // ---- S2: pure MFMA + LDS reads ----
#pragma unroll
        for (int nt = 0; nt < 4; ++nt) accp[nt] = (f32x4){0.f, 0.f, 0.f, 0.f};
        __builtin_amdgcn_s_setprio(1);
#pragma unroll
        for (int kt = 0; kt < 4; ++kt) {
            const int co = kt * 32 + g * 8;
            const int sa = w * 16 + lr;
            f16x8 af = *(const f16x8*)&xT[sa * 128 + (co ^ SWZ_S(sa))];
#pragma unroll
            for (int nt = 0; nt < 4; ++nt) {
                f16x8 wf = *(const f16x8*)&Wlds[(nt * 16 + lr) * 128 + (co ^ fsw16)];
                accp[nt] = __builtin_amdgcn_mfma_f32_16x16x32_f16(af, wf, accp[nt], 0, 0, 0);
            }
        }
        if (it > 0) {
            const unsigned char* xcp = xC8[bb ^ 1];
#pragma unroll
            for (int kt = 0; kt < 2; ++kt) {
                const int so = kt * 32 + g * 8;
                long pa = *(const long*)&sst8[(w * 16 + lr) * 64 + (so ^ fsw8)];
#pragma unroll
                for (int nt = 0; nt < 8; ++nt) {
                    long xv = *(const long*)&xcp[(nt * 16 + lr) * 64 + (so ^ fsw8)];
                    vacc[nt] = __builtin_amdgcn_mfma_f32_16x16x32_fp8_fp8(pa, xv, vacc[nt], 0, 0, 0);
                }
            }
        }
        __builtin_amdgcn_s_setprio(0);
    }

    // ---- epilogue: softmax(cnt-1) -> sst8, then vlad(cnt-1) ----
    const int lastb = (cnt - 1) & 1;
    __syncthreads();
    softmax_emit(lastb);
    __syncthreads();
    {
        const unsigned char* xcp = xC8[lastb];
#pragma unroll
        for (int kt = 0; kt < 2; ++kt) {
            const int so = kt * 32 + g * 8;
            long pa = *(const long*)&sst8[(w * 16 + lr) * 64 + (so ^ fsw8)];
#pragma unroll
            for (int nt = 0; nt < 8; ++nt) {
                long xv = *(const long*)&xcp[(nt * 16 + lr) * 64 + (so ^ fsw8)];
                vacc[nt] = __builtin_amdgcn_mfma_f32_16x16x32_fp8_fp8(pa, xv, vacc[nt], 0, 0, 0);
            }
        }
    }

    // ---- flush: plain stores to this block's slab (unscale /256) ----
    float* vp = vlad_part + (size_t)sl * (K_ * C_) + (w * 16) * C_;
#pragma unroll
    for (int nt = 0; nt < 8; ++nt)
#pragma unroll
        for (int r = 0; r < 4; ++r)
            vp[(g * 4 + r) * C_ + nt * 16 + lr] = vacc[nt][r] * (1.0f / 256.0f);
#pragma unroll
    for (int nt = 0; nt < 4; ++nt) {
        a_acc[nt] += __shfl_xor(a_acc[nt], 16);
        a_acc[nt] += __shfl_xor(a_acc[nt], 32);
    }
    if (lane < 16) {
#pragma unroll
        for (int nt = 0; nt < 4; ++nt)
            a_part[sl * 256 + w * 64 + nt * 16 + lr] = a_acc[nt];
    }
}

// ---------------------------------------------------------------------------
// Reduce: vlad_sum[n][e] = sum_{j<48} vlad_part[n*48+j][e]
// ---------------------------------------------------------------------------
__global__ __launch_bounds__(256) void reduce_kernel(
    const float* __restrict__ vlad_part, float* __restrict__ vlad_sum)
{
    const int n = blockIdx.x >> 5, g8 = blockIdx.x & 31;
    const int e = g8 * 256 + threadIdx.x;
    const float* p = vlad_part + (size_t)(n * 48) * (K_ * C_) + e;
    float acc = 0.f;
#pragma unroll
    for (int jj = 0; jj < 48; ++jj) acc += p[(size_t)jj * (K_ * C_)];
    vlad_sum[n * (K_ * C_) + e] = acc;
}

// ---------------------------------------------------------------------------
// Finalize: a_sum reduce; vlad -= a_sum*centroids; intra-norm; global norm.
// ---------------------------------------------------------------------------
__global__ __launch_bounds__(1024) void finalize_kernel(
    const float* __restrict__ vlad_sum, const float* __restrict__ a_part,
    const float* __restrict__ centroids, float* __restrict__ out)
{
    __shared__ float red[16];
    const int n = blockIdx.x;
    const int t = threadIdx.x;
    const int k = t >> 4, q = t & 15;

    float av = 0.f;
#pragma unroll
    for (int cc = 0; cc < 3; ++cc) {
        int ch = q * 3 + cc;
        const float* ap = a_part + (size_t)(n * 48 + ch) * 256 + k;
#pragma unroll
        for (int ww = 0; ww < 4; ++ww) av += ap[ww * 64];
    }
    av += __shfl_xor(av, 1);
    av += __shfl_xor(av, 2);
    av += __shfl_xor(av, 4);
    av += __shfl_xor(av, 8);

    const float* vp = vlad_sum + (size_t)n * (K_ * C_) + k * C_;
    const float* cp = centroids + k * C_;
    float v[8];
    float ssq = 0.f;
#pragma unroll
    for (int jj = 0; jj < 8; ++jj) {
        int c = q + 16 * jj;
        float val = vp[c] - av * cp[c];
        v[jj] = val;
        ssq += val * val;
    }
    ssq += __shfl_xor(ssq, 1);
    ssq += __shfl_xor(ssq, 2);
    ssq += __shfl_xor(ssq, 4);
    ssq += __shfl_xor(ssq, 8);
    const float inv1 = 1.0f / fmaxf(sqrtf(ssq), 1e-12f);

    float gp = (q == 0) ? ssq * inv1 * inv1 : 0.f;
#pragma unroll
    for (int off = 1; off < 64; off <<= 1) gp += __shfl_xor(gp, off);
    if ((t & 63) == 0) red[t >> 6] = gp;
    __syncthreads();
    float G = 0.f;
#pragma unroll
    for (int i = 0; i < 16; ++i) G += red[i];
    const float ginv = 1.0f / fmaxf(sqrtf(G), 1e-12f);

    float* op = out + (size_t)n * (K_ * C_) + k * C_;
#pragma unroll
    for (int jj = 0; jj < 8; ++jj) op[q + 16 * jj] = v[jj] * inv1 * ginv;
}

extern "C" void kernel_launch(void* const* d_in, const int* in_sizes, int n_in,
                              void* d_out, int out_size, void* d_ws, size_t ws_size,
                              hipStream_t stream) {
    const float* x     = (const float*)d_in[0];
    const float* fc_w  = (const float*)d_in[1];
    const float* fc_b  = (const float*)d_in[2];
    const float* cent  = (const float*)d_in[3];
    float* out = (float*)d_out;

    char* ws = (char*)d_ws;
    float* vlad_part = (float*)ws;                                    // 25.2 MB
    float* a_part    = (float*)(ws + (size_t)768 * K_ * C_ * 4);      // 768 KB
    float* vlad_sum  = (float*)(ws + (size_t)768 * K_ * C_ * 4 + 786432);

    fused_kernel<<<768, 256, 0, stream>>>(x, fc_w, fc_b, vlad_part, a_part);
    reduce_kernel<<<512, 256, 0, stream>>>(vlad_part, vlad_sum);
    finalize_kernel<<<N_, 1024, 0, stream>>>(vlad_sum, a_part, cent, out);
}